// Round 2
// baseline (1654.599 us; speedup 1.0000x reference)
//
#include <hip/hip_runtime.h>
#include <stdint.h>
#include <math.h>

#define DEV static __device__ __forceinline__

// ---------------- Threefry-2x32/20 (exact JAX schedule) ----------------
DEV uint32_t rotl32(uint32_t v, int d) { return (v << d) | (v >> (32 - d)); }

DEV void threefry2x32(uint32_t k0, uint32_t k1, uint32_t& x0, uint32_t& x1) {
  const uint32_t k2 = k0 ^ k1 ^ 0x1BD11BDAu;
  x0 += k0; x1 += k1;
#define TFR(R) { x0 += x1; x1 = rotl32(x1, R) ^ x0; }
  TFR(13) TFR(15) TFR(26) TFR(6)
  x0 += k1; x1 += k2 + 1u;
  TFR(17) TFR(29) TFR(16) TFR(24)
  x0 += k2; x1 += k0 + 2u;
  TFR(13) TFR(15) TFR(26) TFR(6)
  x0 += k0; x1 += k1 + 3u;
  TFR(17) TFR(29) TFR(16) TFR(24)
  x0 += k1; x1 += k2 + 4u;
  TFR(13) TFR(15) TFR(26) TFR(6)
  x0 += k2; x1 += k0 + 5u;
#undef TFR
}

// ---------------- erfinv (XLA f32 ErfInv, Giles 2012) ----------------
DEV float erfinv_f32(float x) {
  float w = -log1pf(-x * x);
  float p;
  if (w < 5.0f) {
    w -= 2.5f;
    p = 2.81022636e-08f;
    p = fmaf(p, w, 3.43273939e-07f);
    p = fmaf(p, w, -3.5233877e-06f);
    p = fmaf(p, w, -4.39150654e-06f);
    p = fmaf(p, w, 0.00021858087f);
    p = fmaf(p, w, -0.00125372503f);
    p = fmaf(p, w, -0.00417768164f);
    p = fmaf(p, w, 0.246640727f);
    p = fmaf(p, w, 1.50140941f);
  } else {
    w = sqrtf(w) - 3.0f;
    p = -0.000200214257f;
    p = fmaf(p, w, 0.000100950558f);
    p = fmaf(p, w, 0.00134934322f);
    p = fmaf(p, w, -0.00367342844f);
    p = fmaf(p, w, 0.00573950773f);
    p = fmaf(p, w, -0.0076224613f);
    p = fmaf(p, w, 0.00943887047f);
    p = fmaf(p, w, 1.00167406f);
    p = fmaf(p, w, 2.83297682f);
  }
  return p * x;
}

DEV float normal_from_bits(uint32_t bits) {
  // jax.random.uniform: bitcast((bits>>9)|0x3f800000) - 1 in [0,1)
  float f = __uint_as_float((bits >> 9) | 0x3F800000u) - 1.0f;
  const float lo = -0.99999994f;            // nextafter(-1, 0) in f32
  float u = fmaf(f, 2.0f, lo);              // (maxval-minval) rounds to 2.0f
  u = fmaxf(u, lo);
  return 1.41421356f * erfinv_f32(u);       // sqrt(2) * erfinv(u)
}

// ---------------- graph-norm kernels ----------------
__global__ void deg_kernel(const int* __restrict__ rows, const int* __restrict__ cols,
                           float* __restrict__ deg, int E) {
  int e = blockIdx.x * blockDim.x + threadIdx.x;
  if (e < E) {
    int r = rows[e];
    if (r != cols[e]) atomicAdd(&deg[r], 1.0f);
  }
}

__global__ void dinv_kernel(float* __restrict__ deg, int N) {
  int i = blockIdx.x * blockDim.x + threadIdx.x;
  if (i < N) {
    float d = deg[i];
    deg[i] = d > 0.0f ? 1.0f / sqrtf(d) : 0.0f;
  }
}

__global__ void normw_kernel(const int* __restrict__ rows, const int* __restrict__ cols,
                             const float* __restrict__ dinv, float* __restrict__ nw, int E) {
  int e = blockIdx.x * blockDim.x + threadIdx.x;
  if (e < E) {
    int r = rows[e], c = cols[e];
    nw[e] = (r != c) ? -dinv[r] * dinv[c] : 0.0f;
  }
}

// ---------------- propagation: out[row] += scale*nw[e]*x[col] ----------------
__global__ void scatter_kernel(const int* __restrict__ rows, const int* __restrict__ cols,
                               const float* __restrict__ nw, const float* __restrict__ x,
                               float* __restrict__ out, int F, float scale) {
  int e = blockIdx.x;
  int f = blockIdx.y * blockDim.x + threadIdx.x;
  if (f >= F) return;
  float w = nw[e];
  if (w == 0.0f) return;
  w *= scale;
  atomicAdd(&out[(size_t)rows[e] * F + f], w * x[(size_t)cols[e] * F + f]);
}

__global__ void negcopy_kernel(const float* __restrict__ x, float* __restrict__ y, int n) {
  int i = blockIdx.x * blockDim.x + threadIdx.x;
  if (i < n) y[i] = -x[i];
}

// ---------------- fused 3-operand GEMM + bias + ReLU ----------------
// out[m,o] = relu( A0@W[0] + A1@W[1] + A2@W[2] + b ),  W: [3, F, O] row-major
#define BK 16
__global__ __launch_bounds__(256) void gemm3_relu_kernel(
    const float* __restrict__ A0, const float* __restrict__ A1, const float* __restrict__ A2,
    const float* __restrict__ W, const float* __restrict__ bias,
    int M, int F, int O, float* __restrict__ out) {
  __shared__ float sA[BK][64 + 1];
  __shared__ float sB[BK][64];
  const int tx = threadIdx.x & 15;
  const int ty = threadIdx.x >> 4;
  const int bm = blockIdx.x * 64;
  const int bo = blockIdx.y * 64;
  float acc[4][4] = {};
  for (int p = 0; p < 3; ++p) {
    const float* __restrict__ A = (p == 0) ? A0 : ((p == 1) ? A1 : A2);
    const float* __restrict__ Wp = W + (size_t)p * F * O;
    for (int k0 = 0; k0 < F; k0 += BK) {
      for (int t = threadIdx.x; t < 64 * BK; t += 256) {
        int m = t >> 4, kk = t & 15;
        int gm = bm + m, gk = k0 + kk;
        sA[kk][m] = (gm < M && gk < F) ? A[(size_t)gm * F + gk] : 0.0f;
      }
      for (int t = threadIdx.x; t < BK * 64; t += 256) {
        int kk = t >> 6, o = t & 63;
        int gk = k0 + kk;
        sB[kk][o] = (gk < F) ? Wp[(size_t)gk * O + bo + o] : 0.0f;
      }
      __syncthreads();
      for (int kk = 0; kk < BK; ++kk) {
        float a[4], bv[4];
#pragma unroll
        for (int i = 0; i < 4; ++i) a[i] = sA[kk][ty * 4 + i];
#pragma unroll
        for (int j = 0; j < 4; ++j) bv[j] = sB[kk][tx * 4 + j];
#pragma unroll
        for (int i = 0; i < 4; ++i)
#pragma unroll
          for (int j = 0; j < 4; ++j) acc[i][j] = fmaf(a[i], bv[j], acc[i][j]);
      }
      __syncthreads();
    }
  }
#pragma unroll
  for (int i = 0; i < 4; ++i) {
    int gm = bm + ty * 4 + i;
    if (gm >= M) continue;
#pragma unroll
    for (int j = 0; j < 4; ++j) {
      int go = bo + tx * 4 + j;
      float v = acc[i][j] + bias[go];
      out[(size_t)gm * O + go] = v > 0.0f ? v : 0.0f;
    }
  }
}

// ---------------- noise: x[i] *= N(0,1), partitionable threefry ----------------
// bits(i) = out0 ^ out1 of threefry(fold_in(key(42),FOLD), (0, i))
template <int FOLD>
__global__ void noise_mul_kernel(float* __restrict__ x, int n) {
  // fold_in(key=(0,42), FOLD): constant-folded at compile time
  uint32_t f0 = 0u, f1 = (uint32_t)FOLD;
  threefry2x32(0u, 42u, f0, f1);
  int i = blockIdx.x * blockDim.x + threadIdx.x;
  if (i >= n) return;
  uint32_t a = 0u, b = (uint32_t)i;
  threefry2x32(f0, f1, a, b);
  uint32_t bits = a ^ b;   // partitionable path XORs the two output words
  x[i] *= normal_from_bits(bits);
}

static void launch_noise(float* x, int n, int fold, hipStream_t s) {
  int blocks = (n + 255) / 256;
  switch (fold) {
    case 1: noise_mul_kernel<1><<<blocks, 256, 0, s>>>(x, n); break;
    case 2: noise_mul_kernel<2><<<blocks, 256, 0, s>>>(x, n); break;
    case 3: noise_mul_kernel<3><<<blocks, 256, 0, s>>>(x, n); break;
  }
}

// ---------------- host orchestration ----------------
extern "C" void kernel_launch(void* const* d_in, const int* in_sizes, int n_in,
                              void* d_out, int out_size, void* d_ws, size_t ws_size,
                              hipStream_t stream) {
  const float* v    = (const float*)d_in[0];
  const int*  edges = (const int*)d_in[1];
  const float* W1 = (const float*)d_in[2];
  const float* b1 = (const float*)d_in[3];
  const float* W2 = (const float*)d_in[4];
  const float* b2 = (const float*)d_in[5];
  const float* W3 = (const float*)d_in[6];
  const float* b3 = (const float*)d_in[7];
  float* out = (float*)d_out;

  const int N = in_sizes[0] / 86;
  const int E = in_sizes[1] / 2;
  const int* rows = edges;
  const int* cols = edges + E;

  // workspace layout (floats): deg/dinv [N] | norm_w [E] | tx1 [N*256] | tx2 [N*256]
  float* wsf  = (float*)d_ws;
  float* dinv = wsf;
  float* nw   = wsf + N;
  float* tx1  = nw + E;
  float* tx2  = tx1 + (size_t)N * 256;

  float* x1 = out;
  float* x2 = x1 + (size_t)N * 128;
  float* x3 = x2 + (size_t)N * 256;

  // graph norm
  hipMemsetAsync(dinv, 0, (size_t)N * sizeof(float), stream);
  deg_kernel<<<(E + 255) / 256, 256, 0, stream>>>(rows, cols, dinv, E);
  dinv_kernel<<<(N + 255) / 256, 256, 0, stream>>>(dinv, N);
  normw_kernel<<<(E + 255) / 256, 256, 0, stream>>>(rows, cols, dinv, nw, E);

  auto layer = [&](const float* xin, int F, int O, const float* W, const float* b,
                   float* xout, int fold) {
    size_t nf = (size_t)N * F;
    // Tx1 = P x
    hipMemsetAsync(tx1, 0, nf * sizeof(float), stream);
    {
      dim3 grid(E, (F + 127) / 128);
      scatter_kernel<<<grid, 128, 0, stream>>>(rows, cols, nw, xin, tx1, F, 1.0f);
    }
    // Tx2 = 2*P*Tx1 - x
    negcopy_kernel<<<(int)((nf + 255) / 256), 256, 0, stream>>>(xin, tx2, (int)nf);
    {
      dim3 grid(E, (F + 127) / 128);
      scatter_kernel<<<grid, 128, 0, stream>>>(rows, cols, nw, tx1, tx2, F, 2.0f);
    }
    // out = relu(x@W0 + tx1@W1 + tx2@W2 + b)
    {
      dim3 grid((N + 63) / 64, O / 64);
      gemm3_relu_kernel<<<grid, 256, 0, stream>>>(xin, tx1, tx2, W, b, N, F, O, xout);
    }
    launch_noise(xout, N * O, fold, stream);
  };

  layer(v,  86, 128, W1, b1, x1, 1);
  layer(x1, 128, 256, W2, b2, x2, 2);
  layer(x2, 256, 512, W3, b3, x3, 3);
}

// Round 3
// 1062.486 us; speedup vs baseline: 1.5573x; 1.5573x over previous
//
#include <hip/hip_runtime.h>
#include <stdint.h>
#include <math.h>

#define DEV static __device__ __forceinline__

// ---------------- Threefry-2x32/20 (exact JAX schedule) ----------------
DEV uint32_t rotl32(uint32_t v, int d) { return (v << d) | (v >> (32 - d)); }

DEV void threefry2x32(uint32_t k0, uint32_t k1, uint32_t& x0, uint32_t& x1) {
  const uint32_t k2 = k0 ^ k1 ^ 0x1BD11BDAu;
  x0 += k0; x1 += k1;
#define TFR(R) { x0 += x1; x1 = rotl32(x1, R) ^ x0; }
  TFR(13) TFR(15) TFR(26) TFR(6)
  x0 += k1; x1 += k2 + 1u;
  TFR(17) TFR(29) TFR(16) TFR(24)
  x0 += k2; x1 += k0 + 2u;
  TFR(13) TFR(15) TFR(26) TFR(6)
  x0 += k0; x1 += k1 + 3u;
  TFR(17) TFR(29) TFR(16) TFR(24)
  x0 += k1; x1 += k2 + 4u;
  TFR(13) TFR(15) TFR(26) TFR(6)
  x0 += k2; x1 += k0 + 5u;
#undef TFR
}

// ---------------- erfinv (XLA f32 ErfInv, Giles 2012) ----------------
DEV float erfinv_f32(float x) {
  float w = -log1pf(-x * x);
  float p;
  if (w < 5.0f) {
    w -= 2.5f;
    p = 2.81022636e-08f;
    p = fmaf(p, w, 3.43273939e-07f);
    p = fmaf(p, w, -3.5233877e-06f);
    p = fmaf(p, w, -4.39150654e-06f);
    p = fmaf(p, w, 0.00021858087f);
    p = fmaf(p, w, -0.00125372503f);
    p = fmaf(p, w, -0.00417768164f);
    p = fmaf(p, w, 0.246640727f);
    p = fmaf(p, w, 1.50140941f);
  } else {
    w = sqrtf(w) - 3.0f;
    p = -0.000200214257f;
    p = fmaf(p, w, 0.000100950558f);
    p = fmaf(p, w, 0.00134934322f);
    p = fmaf(p, w, -0.00367342844f);
    p = fmaf(p, w, 0.00573950773f);
    p = fmaf(p, w, -0.0076224613f);
    p = fmaf(p, w, 0.00943887047f);
    p = fmaf(p, w, 1.00167406f);
    p = fmaf(p, w, 2.83297682f);
  }
  return p * x;
}

DEV float normal_from_bits(uint32_t bits) {
  float f = __uint_as_float((bits >> 9) | 0x3F800000u) - 1.0f;
  const float lo = -0.99999994f;            // nextafter(-1, 0) in f32
  float u = fmaf(f, 2.0f, lo);
  u = fmaxf(u, lo);
  return 1.41421356f * erfinv_f32(u);
}

// ---------------- CSR build ----------------
__global__ void count_kernel(const int* __restrict__ rows, const int* __restrict__ cols,
                             int* __restrict__ counts, int* __restrict__ degs, int E) {
  int e = blockIdx.x * blockDim.x + threadIdx.x;
  if (e < E) {
    int r = rows[e];
    atomicAdd(&counts[r], 1);
    if (r != cols[e]) atomicAdd(&degs[r], 1);
  }
}

__global__ void dinv_kernel(const int* __restrict__ degs, float* __restrict__ dinv, int N) {
  int i = blockIdx.x * blockDim.x + threadIdx.x;
  if (i < N) {
    int d = degs[i];
    dinv[i] = d > 0 ? rsqrtf((float)d) : 0.0f;
  }
}

// single-block exclusive scan of counts[N] -> row_ptr[N+1]; also seeds cursor = row_ptr
#define SCAN_T 1024
__global__ __launch_bounds__(SCAN_T) void scan_kernel(const int* __restrict__ counts,
                                                      int* __restrict__ row_ptr,
                                                      int* __restrict__ cursor, int N) {
  __shared__ int sa[SCAN_T], sb[SCAN_T];
  const int t = threadIdx.x;
  const int CH = (N + SCAN_T - 1) / SCAN_T;
  int base = t * CH;
  int psum = 0;
  for (int k = 0; k < CH; ++k) {
    int idx = base + k;
    if (idx < N) psum += counts[idx];
  }
  sa[t] = psum;
  __syncthreads();
  // Hillis-Steele inclusive scan over SCAN_T partials
  int* src = sa; int* dst = sb;
  for (int off = 1; off < SCAN_T; off <<= 1) {
    int v = src[t];
    if (t >= off) v += src[t - off];
    dst[t] = v;
    __syncthreads();
    int* tmp = src; src = dst; dst = tmp;
  }
  int running = src[t] - psum;  // exclusive prefix for this thread's chunk
  for (int k = 0; k < CH; ++k) {
    int idx = base + k;
    if (idx < N) {
      row_ptr[idx] = running;
      cursor[idx] = running;
      running += counts[idx];
    }
  }
  if (t == SCAN_T - 1) row_ptr[N] = running;
}

__global__ void fill_kernel(const int* __restrict__ rows, const int* __restrict__ cols,
                            const float* __restrict__ dinv, int* __restrict__ cursor,
                            float2* __restrict__ ecv, int E) {
  int e = blockIdx.x * blockDim.x + threadIdx.x;
  if (e < E) {
    int r = rows[e], c = cols[e];
    float w = (r != c) ? -dinv[r] * dinv[c] : 0.0f;
    int pos = atomicAdd(&cursor[r], 1);
    ecv[pos] = make_float2(__int_as_float(c), w);
  }
}

// ---------------- propagation via CSR gather ----------------
// SUB=0: out[i,f] = sum_e w*xsrc[col,f]
// SUB=1: out[i,f] = 2*sum_e w*xsrc[col,f] - xsub[i,f]
template <int SUB>
__global__ __launch_bounds__(256) void gather_prop_kernel(
    const int* __restrict__ row_ptr, const float2* __restrict__ ecv,
    const float* __restrict__ xsrc, const float* __restrict__ xsub,
    float* __restrict__ outp, int N, int F) {
  const int wv = threadIdx.x >> 6;
  const int lane = threadIdx.x & 63;
  const int node = blockIdx.x * 4 + wv;
  const int f = blockIdx.y * 64 + lane;
  if (node >= N || f >= F) return;
  const int s = row_ptr[node], epos = row_ptr[node + 1];
  float acc = 0.0f;
  for (int j = s; j < epos; ++j) {
    float2 cw = ecv[j];                       // wave-uniform -> broadcast
    int c = __float_as_int(cw.x);
    acc = fmaf(cw.y, xsrc[(size_t)c * F + f], acc);
  }
  size_t o = (size_t)node * F + f;
  if (SUB) outp[o] = fmaf(2.0f, acc, -xsub[o]);
  else     outp[o] = acc;
}

// ---------------- fused 3-operand GEMM + bias + ReLU + noise ----------------
// out[m,o] = relu( A0@W[0] + A1@W[1] + A2@W[2] + b ) * N(0,1)[m*O+o]
#define BK 16
__global__ __launch_bounds__(256) void gemm3_relu_noise_kernel(
    const float* __restrict__ A0, const float* __restrict__ A1, const float* __restrict__ A2,
    const float* __restrict__ W, const float* __restrict__ bias,
    int M, int F, int O, float* __restrict__ out, int fold) {
  __shared__ float sA[BK][64 + 1];
  __shared__ float sB[BK][64];
  const int tx = threadIdx.x & 15;
  const int ty = threadIdx.x >> 4;
  const int bm = blockIdx.x * 64;
  const int bo = blockIdx.y * 64;
  float acc[4][4] = {};
  for (int p = 0; p < 3; ++p) {
    const float* __restrict__ A = (p == 0) ? A0 : ((p == 1) ? A1 : A2);
    const float* __restrict__ Wp = W + (size_t)p * F * O;
    for (int k0 = 0; k0 < F; k0 += BK) {
      for (int t = threadIdx.x; t < 64 * BK; t += 256) {
        int m = t >> 4, kk = t & 15;
        int gm = bm + m, gk = k0 + kk;
        sA[kk][m] = (gm < M && gk < F) ? A[(size_t)gm * F + gk] : 0.0f;
      }
      for (int t = threadIdx.x; t < BK * 64; t += 256) {
        int kk = t >> 6, o = t & 63;
        int gk = k0 + kk;
        sB[kk][o] = (gk < F) ? Wp[(size_t)gk * O + bo + o] : 0.0f;
      }
      __syncthreads();
      for (int kk = 0; kk < BK; ++kk) {
        float a[4], bv[4];
#pragma unroll
        for (int i = 0; i < 4; ++i) a[i] = sA[kk][ty * 4 + i];
#pragma unroll
        for (int j = 0; j < 4; ++j) bv[j] = sB[kk][tx * 4 + j];
#pragma unroll
        for (int i = 0; i < 4; ++i)
#pragma unroll
          for (int j = 0; j < 4; ++j) acc[i][j] = fmaf(a[i], bv[j], acc[i][j]);
      }
      __syncthreads();
    }
  }
  // fold_in(key=(0,42), fold)
  uint32_t f0 = 0u, f1 = (uint32_t)fold;
  threefry2x32(0u, 42u, f0, f1);
#pragma unroll
  for (int i = 0; i < 4; ++i) {
    int gm = bm + ty * 4 + i;
    if (gm >= M) continue;
#pragma unroll
    for (int j = 0; j < 4; ++j) {
      int go = bo + tx * 4 + j;
      float v = acc[i][j] + bias[go];
      v = v > 0.0f ? v : 0.0f;
      uint32_t idx = (uint32_t)(gm * O + go);
      uint32_t a = 0u, b = idx;
      threefry2x32(f0, f1, a, b);
      out[(size_t)gm * O + go] = v * normal_from_bits(a ^ b);
    }
  }
}

// ---------------- host orchestration ----------------
extern "C" void kernel_launch(void* const* d_in, const int* in_sizes, int n_in,
                              void* d_out, int out_size, void* d_ws, size_t ws_size,
                              hipStream_t stream) {
  const float* v    = (const float*)d_in[0];
  const int*  edges = (const int*)d_in[1];
  const float* W1 = (const float*)d_in[2];
  const float* b1 = (const float*)d_in[3];
  const float* W2 = (const float*)d_in[4];
  const float* b2 = (const float*)d_in[5];
  const float* W3 = (const float*)d_in[6];
  const float* b3 = (const float*)d_in[7];
  float* out = (float*)d_out;

  const int N = in_sizes[0] / 86;
  const int E = in_sizes[1] / 2;
  const int* rows = edges;
  const int* cols = edges + E;

  // ws layout (floats): ecv[2E] | tx1[N*256] | tx2[N*256] | counts[N] | degs[N] | row_ptr[N+1] | cursor[N] | dinv[N]
  float* wsf = (float*)d_ws;
  float2* ecv = (float2*)wsf;
  float* tx1 = wsf + (size_t)2 * E;
  float* tx2 = tx1 + (size_t)N * 256;
  int* counts = (int*)(tx2 + (size_t)N * 256);
  int* degs = counts + N;
  int* row_ptr = degs + N;
  int* cursor = row_ptr + (N + 1);
  float* dinv = (float*)(cursor + N);

  float* x1 = out;
  float* x2 = x1 + (size_t)N * 128;
  float* x3 = x2 + (size_t)N * 256;

  // CSR build + norm
  hipMemsetAsync(counts, 0, (size_t)2 * N * sizeof(int), stream);  // counts + degs
  count_kernel<<<(E + 255) / 256, 256, 0, stream>>>(rows, cols, counts, degs, E);
  dinv_kernel<<<(N + 255) / 256, 256, 0, stream>>>(degs, dinv, N);
  scan_kernel<<<1, SCAN_T, 0, stream>>>(counts, row_ptr, cursor, N);
  fill_kernel<<<(E + 255) / 256, 256, 0, stream>>>(rows, cols, dinv, cursor, ecv, E);

  auto layer = [&](const float* xin, int F, int O, const float* W, const float* b,
                   float* xout, int fold) {
    dim3 pgrid((N + 3) / 4, (F + 63) / 64);
    gather_prop_kernel<0><<<pgrid, 256, 0, stream>>>(row_ptr, ecv, xin, nullptr, tx1, N, F);
    gather_prop_kernel<1><<<pgrid, 256, 0, stream>>>(row_ptr, ecv, tx1, xin, tx2, N, F);
    dim3 ggrid((N + 63) / 64, O / 64);
    gemm3_relu_noise_kernel<<<ggrid, 256, 0, stream>>>(xin, tx1, tx2, W, b, N, F, O, xout, fold);
  };

  layer(v,  86, 128, W1, b1, x1, 1);
  layer(x1, 128, 256, W2, b2, x2, 2);
  layer(x2, 256, 512, W3, b3, x3, 3);
}

// Round 4
// 759.486 us; speedup vs baseline: 2.1786x; 1.3990x over previous
//
#include <hip/hip_runtime.h>
#include <stdint.h>
#include <math.h>

#define DEV static __device__ __forceinline__

typedef __attribute__((ext_vector_type(8))) short bf16x8;
typedef __attribute__((ext_vector_type(4))) float f32x4;
typedef __attribute__((ext_vector_type(8))) unsigned short u16x8;

// ---------------- Threefry-2x32/20 (exact JAX schedule) ----------------
DEV uint32_t rotl32(uint32_t v, int d) { return (v << d) | (v >> (32 - d)); }

DEV void threefry2x32(uint32_t k0, uint32_t k1, uint32_t& x0, uint32_t& x1) {
  const uint32_t k2 = k0 ^ k1 ^ 0x1BD11BDAu;
  x0 += k0; x1 += k1;
#define TFR(R) { x0 += x1; x1 = rotl32(x1, R) ^ x0; }
  TFR(13) TFR(15) TFR(26) TFR(6)
  x0 += k1; x1 += k2 + 1u;
  TFR(17) TFR(29) TFR(16) TFR(24)
  x0 += k2; x1 += k0 + 2u;
  TFR(13) TFR(15) TFR(26) TFR(6)
  x0 += k0; x1 += k1 + 3u;
  TFR(17) TFR(29) TFR(16) TFR(24)
  x0 += k1; x1 += k2 + 4u;
  TFR(13) TFR(15) TFR(26) TFR(6)
  x0 += k2; x1 += k0 + 5u;
#undef TFR
}

// ---------------- erfinv (XLA f32 ErfInv, Giles 2012) ----------------
DEV float erfinv_f32(float x) {
  float w = -log1pf(-x * x);
  float p;
  if (w < 5.0f) {
    w -= 2.5f;
    p = 2.81022636e-08f;
    p = fmaf(p, w, 3.43273939e-07f);
    p = fmaf(p, w, -3.5233877e-06f);
    p = fmaf(p, w, -4.39150654e-06f);
    p = fmaf(p, w, 0.00021858087f);
    p = fmaf(p, w, -0.00125372503f);
    p = fmaf(p, w, -0.00417768164f);
    p = fmaf(p, w, 0.246640727f);
    p = fmaf(p, w, 1.50140941f);
  } else {
    w = sqrtf(w) - 3.0f;
    p = -0.000200214257f;
    p = fmaf(p, w, 0.000100950558f);
    p = fmaf(p, w, 0.00134934322f);
    p = fmaf(p, w, -0.00367342844f);
    p = fmaf(p, w, 0.00573950773f);
    p = fmaf(p, w, -0.0076224613f);
    p = fmaf(p, w, 0.00943887047f);
    p = fmaf(p, w, 1.00167406f);
    p = fmaf(p, w, 2.83297682f);
  }
  return p * x;
}

DEV float normal_from_bits(uint32_t bits) {
  float f = __uint_as_float((bits >> 9) | 0x3F800000u) - 1.0f;
  const float lo = -0.99999994f;            // nextafter(-1, 0) in f32
  float u = fmaf(f, 2.0f, lo);
  u = fmaxf(u, lo);
  return 1.41421356f * erfinv_f32(u);
}

DEV unsigned short f2bf(float f) {   // RTNE f32 -> bf16
  uint32_t u = __float_as_uint(f);
  uint32_t r = u + 0x7FFFu + ((u >> 16) & 1u);
  return (unsigned short)(r >> 16);
}

// ---------------- CSR build ----------------
__global__ void count_kernel(const int* __restrict__ rows, const int* __restrict__ cols,
                             int* __restrict__ counts, int* __restrict__ degs, int E) {
  int e = blockIdx.x * blockDim.x + threadIdx.x;
  if (e < E) {
    int r = rows[e];
    atomicAdd(&counts[r], 1);
    if (r != cols[e]) atomicAdd(&degs[r], 1);
  }
}

__global__ void dinv_kernel(const int* __restrict__ degs, float* __restrict__ dinv, int N) {
  int i = blockIdx.x * blockDim.x + threadIdx.x;
  if (i < N) {
    int d = degs[i];
    dinv[i] = d > 0 ? rsqrtf((float)d) : 0.0f;
  }
}

#define SCAN_T 1024
__global__ __launch_bounds__(SCAN_T) void scan_kernel(const int* __restrict__ counts,
                                                      int* __restrict__ row_ptr,
                                                      int* __restrict__ cursor, int N) {
  __shared__ int sa[SCAN_T], sb[SCAN_T];
  const int t = threadIdx.x;
  const int CH = (N + SCAN_T - 1) / SCAN_T;
  int base = t * CH;
  int psum = 0;
  for (int k = 0; k < CH; ++k) {
    int idx = base + k;
    if (idx < N) psum += counts[idx];
  }
  sa[t] = psum;
  __syncthreads();
  int* src = sa; int* dst = sb;
  for (int off = 1; off < SCAN_T; off <<= 1) {
    int v = src[t];
    if (t >= off) v += src[t - off];
    dst[t] = v;
    __syncthreads();
    int* tmp = src; src = dst; dst = tmp;
  }
  int running = src[t] - psum;
  for (int k = 0; k < CH; ++k) {
    int idx = base + k;
    if (idx < N) {
      row_ptr[idx] = running;
      cursor[idx] = running;
      running += counts[idx];
    }
  }
  if (t == SCAN_T - 1) row_ptr[N] = running;
}

__global__ void fill_kernel(const int* __restrict__ rows, const int* __restrict__ cols,
                            const float* __restrict__ dinv, int* __restrict__ cursor,
                            float2* __restrict__ ecv, int E) {
  int e = blockIdx.x * blockDim.x + threadIdx.x;
  if (e < E) {
    int r = rows[e], c = cols[e];
    float w = (r != c) ? -dinv[r] * dinv[c] : 0.0f;
    int pos = atomicAdd(&cursor[r], 1);
    ecv[pos] = make_float2(__int_as_float(c), w);
  }
}

// ---------------- propagation via CSR gather ----------------
template <int SUB>
__global__ __launch_bounds__(256) void gather_prop_kernel(
    const int* __restrict__ row_ptr, const float2* __restrict__ ecv,
    const float* __restrict__ xsrc, const float* __restrict__ xsub,
    float* __restrict__ outp, int N, int F) {
  const int wv = threadIdx.x >> 6;
  const int lane = threadIdx.x & 63;
  const int node = blockIdx.x * 4 + wv;
  const int f = blockIdx.y * 64 + lane;
  if (node >= N || f >= F) return;
  const int s = row_ptr[node], epos = row_ptr[node + 1];
  float acc = 0.0f;
  for (int j = s; j < epos; ++j) {
    float2 cw = ecv[j];
    int c = __float_as_int(cw.x);
    acc = fmaf(cw.y, xsrc[(size_t)c * F + f], acc);
  }
  size_t o = (size_t)node * F + f;
  if (SUB) outp[o] = fmaf(2.0f, acc, -xsub[o]);
  else     outp[o] = acc;
}

// ---------------- weight transpose+convert: Wt[p][o][k] = bf16(W[p][k][o]) ----------------
__global__ void wtrans_kernel(const float* __restrict__ W, unsigned short* __restrict__ Wt,
                              int F, int Fpad, int O) {
  int idx = blockIdx.x * 256 + threadIdx.x;
  int total = 3 * O * Fpad;
  if (idx >= total) return;
  int k = idx % Fpad;
  int o = (idx / Fpad) % O;
  int p = idx / (Fpad * O);
  Wt[idx] = (k < F) ? f2bf(W[((size_t)p * F + k) * O + o]) : (unsigned short)0;
}

// ---------------- MFMA bf16 GEMM: out = relu(A0@W0+A1@W1+A2@W2+b)*noise ----------------
#define LDST 40   // LDS row stride (bf16 elems): breaks b128 bank conflicts
__global__ __launch_bounds__(256) void gemm3_mfma_kernel(
    const float* __restrict__ A0, const float* __restrict__ A1, const float* __restrict__ A2,
    const unsigned short* __restrict__ Wt,  // [3][O][Fpad] bf16
    const float* __restrict__ bias,
    int M, int F, int Fpad, int O, float* __restrict__ out, int fold) {
  __shared__ unsigned short sA[64 * LDST];
  __shared__ unsigned short sB[64 * LDST];
  const int tid = threadIdx.x;
  const int lane = tid & 63;
  const int wave = tid >> 6;
  const int wm = wave >> 1, wo = wave & 1;
  const int bm = blockIdx.x * 64;
  const int bo = blockIdx.y * 64;
  const int srow = tid >> 2;          // 0..63
  const int schunk = (tid & 3) * 8;   // 0,8,16,24

  f32x4 acc[2][2] = {};

  for (int p = 0; p < 3; ++p) {
    const float* __restrict__ A = (p == 0) ? A0 : ((p == 1) ? A1 : A2);
    const unsigned short* __restrict__ Wp = Wt + (size_t)p * O * Fpad;
    for (int k0 = 0; k0 < Fpad; k0 += 32) {
      __syncthreads();
      // stage A tile (f32 -> bf16)
      {
        int gm = bm + srow;
        int kk = k0 + schunk;
        unsigned short pk[8];
        if (gm < M && kk + 8 <= F) {
#pragma unroll
          for (int j = 0; j < 4; ++j) {
            float2 v2 = *(const float2*)(A + (size_t)gm * F + kk + 2 * j);
            pk[2 * j] = f2bf(v2.x);
            pk[2 * j + 1] = f2bf(v2.y);
          }
        } else {
#pragma unroll
          for (int j = 0; j < 8; ++j) {
            int gk = kk + j;
            pk[j] = (gm < M && gk < F) ? f2bf(A[(size_t)gm * F + gk]) : (unsigned short)0;
          }
        }
        *(u16x8*)&sA[srow * LDST + schunk] = *(u16x8*)pk;
      }
      // stage B tile (already bf16, contiguous rows of Wt)
      {
        int go = bo + srow;
        u16x8 v = *(const u16x8*)(Wp + (size_t)go * Fpad + k0 + schunk);
        *(u16x8*)&sB[srow * LDST + schunk] = v;
      }
      __syncthreads();
      const int kgrp = (lane >> 4) * 8;
      bf16x8 af[2], bfr[2];
#pragma unroll
      for (int mi = 0; mi < 2; ++mi)
        af[mi] = *(const bf16x8*)&sA[(wm * 32 + mi * 16 + (lane & 15)) * LDST + kgrp];
#pragma unroll
      for (int ni = 0; ni < 2; ++ni)
        bfr[ni] = *(const bf16x8*)&sB[(wo * 32 + ni * 16 + (lane & 15)) * LDST + kgrp];
#pragma unroll
      for (int mi = 0; mi < 2; ++mi)
#pragma unroll
        for (int ni = 0; ni < 2; ++ni)
          acc[mi][ni] = __builtin_amdgcn_mfma_f32_16x16x32_bf16(af[mi], bfr[ni], acc[mi][ni], 0, 0, 0);
    }
  }

  // epilogue: bias + relu + threefry noise
  uint32_t f0 = 0u, f1 = (uint32_t)fold;
  threefry2x32(0u, 42u, f0, f1);
  const int col0 = bo + wo * 32 + (lane & 15);
  const int rbase = bm + wm * 32 + (lane >> 4) * 4;
#pragma unroll
  for (int mi = 0; mi < 2; ++mi) {
#pragma unroll
    for (int r = 0; r < 4; ++r) {
      int gm = rbase + mi * 16 + r;
      if (gm >= M) continue;
#pragma unroll
      for (int ni = 0; ni < 2; ++ni) {
        int go = col0 + ni * 16;
        float vv = acc[mi][ni][r] + bias[go];
        vv = vv > 0.0f ? vv : 0.0f;
        uint32_t a = 0u, b = (uint32_t)(gm * O + go);
        threefry2x32(f0, f1, a, b);
        out[(size_t)gm * O + go] = vv * normal_from_bits(a ^ b);
      }
    }
  }
}

// ---------------- host orchestration ----------------
extern "C" void kernel_launch(void* const* d_in, const int* in_sizes, int n_in,
                              void* d_out, int out_size, void* d_ws, size_t ws_size,
                              hipStream_t stream) {
  const float* v    = (const float*)d_in[0];
  const int*  edges = (const int*)d_in[1];
  const float* W1 = (const float*)d_in[2];
  const float* b1 = (const float*)d_in[3];
  const float* W2 = (const float*)d_in[4];
  const float* b2 = (const float*)d_in[5];
  const float* W3 = (const float*)d_in[6];
  const float* b3 = (const float*)d_in[7];
  float* out = (float*)d_out;

  const int N = in_sizes[0] / 86;
  const int E = in_sizes[1] / 2;
  const int* rows = edges;
  const int* cols = edges + E;

  // ws layout (floats): ecv[2E] | tx1[N*256] | tx2[N*256] | Wt[3*512*256 bf16 = 196608 u16]
  //                     | counts[N] | degs[N] | row_ptr[N+1] | cursor[N] | dinv[N]
  float* wsf = (float*)d_ws;
  float2* ecv = (float2*)wsf;
  float* tx1 = wsf + (size_t)2 * E;
  float* tx2 = tx1 + (size_t)N * 256;
  unsigned short* Wt = (unsigned short*)(tx2 + (size_t)N * 256);
  int* counts = (int*)(Wt + 3 * 512 * 256);
  int* degs = counts + N;
  int* row_ptr = degs + N;
  int* cursor = row_ptr + (N + 1);
  float* dinv = (float*)(cursor + N);

  float* x1 = out;
  float* x2 = x1 + (size_t)N * 128;
  float* x3 = x2 + (size_t)N * 256;

  // CSR build + norm
  hipMemsetAsync(counts, 0, (size_t)2 * N * sizeof(int), stream);
  count_kernel<<<(E + 255) / 256, 256, 0, stream>>>(rows, cols, counts, degs, E);
  dinv_kernel<<<(N + 255) / 256, 256, 0, stream>>>(degs, dinv, N);
  scan_kernel<<<1, SCAN_T, 0, stream>>>(counts, row_ptr, cursor, N);
  fill_kernel<<<(E + 255) / 256, 256, 0, stream>>>(rows, cols, dinv, cursor, ecv, E);

  auto layer = [&](const float* xin, int F, int Fpad, int O, const float* W, const float* b,
                   float* xout, int fold) {
    // transpose+convert weights for this layer
    int wtot = 3 * O * Fpad;
    wtrans_kernel<<<(wtot + 255) / 256, 256, 0, stream>>>(W, Wt, F, Fpad, O);
    // props (f32)
    dim3 pgrid((N + 3) / 4, (F + 63) / 64);
    gather_prop_kernel<0><<<pgrid, 256, 0, stream>>>(row_ptr, ecv, xin, nullptr, tx1, N, F);
    gather_prop_kernel<1><<<pgrid, 256, 0, stream>>>(row_ptr, ecv, tx1, xin, tx2, N, F);
    // MFMA GEMM + bias + relu + noise
    dim3 ggrid((N + 63) / 64, O / 64);
    gemm3_mfma_kernel<<<ggrid, 256, 0, stream>>>(xin, tx1, tx2, Wt, b, N, F, Fpad, O, xout, fold);
  };

  layer(v,  86,  96, 128, W1, b1, x1, 1);
  layer(x1, 128, 128, 256, W2, b2, x2, 2);
  layer(x2, 256, 256, 512, W3, b3, x3, 3);
}

// Round 5
// 536.973 us; speedup vs baseline: 3.0813x; 1.4144x over previous
//
#include <hip/hip_runtime.h>
#include <stdint.h>
#include <math.h>

#define DEV static __device__ __forceinline__

typedef __attribute__((ext_vector_type(8))) short bf16x8;
typedef __attribute__((ext_vector_type(4))) float f32x4;
typedef __attribute__((ext_vector_type(8))) unsigned short u16x8;

// ---------------- Threefry-2x32/20 (exact JAX schedule) ----------------
DEV uint32_t rotl32(uint32_t v, int d) { return (v << d) | (v >> (32 - d)); }

DEV void threefry2x32(uint32_t k0, uint32_t k1, uint32_t& x0, uint32_t& x1) {
  const uint32_t k2 = k0 ^ k1 ^ 0x1BD11BDAu;
  x0 += k0; x1 += k1;
#define TFR(R) { x0 += x1; x1 = rotl32(x1, R) ^ x0; }
  TFR(13) TFR(15) TFR(26) TFR(6)
  x0 += k1; x1 += k2 + 1u;
  TFR(17) TFR(29) TFR(16) TFR(24)
  x0 += k2; x1 += k0 + 2u;
  TFR(13) TFR(15) TFR(26) TFR(6)
  x0 += k0; x1 += k1 + 3u;
  TFR(17) TFR(29) TFR(16) TFR(24)
  x0 += k1; x1 += k2 + 4u;
  TFR(13) TFR(15) TFR(26) TFR(6)
  x0 += k2; x1 += k0 + 5u;
#undef TFR
}

// ---------------- erfinv (XLA f32 ErfInv, Giles 2012) ----------------
DEV float erfinv_f32(float x) {
  float w = -log1pf(-x * x);
  float p;
  if (w < 5.0f) {
    w -= 2.5f;
    p = 2.81022636e-08f;
    p = fmaf(p, w, 3.43273939e-07f);
    p = fmaf(p, w, -3.5233877e-06f);
    p = fmaf(p, w, -4.39150654e-06f);
    p = fmaf(p, w, 0.00021858087f);
    p = fmaf(p, w, -0.00125372503f);
    p = fmaf(p, w, -0.00417768164f);
    p = fmaf(p, w, 0.246640727f);
    p = fmaf(p, w, 1.50140941f);
  } else {
    w = sqrtf(w) - 3.0f;
    p = -0.000200214257f;
    p = fmaf(p, w, 0.000100950558f);
    p = fmaf(p, w, 0.00134934322f);
    p = fmaf(p, w, -0.00367342844f);
    p = fmaf(p, w, 0.00573950773f);
    p = fmaf(p, w, -0.0076224613f);
    p = fmaf(p, w, 0.00943887047f);
    p = fmaf(p, w, 1.00167406f);
    p = fmaf(p, w, 2.83297682f);
  }
  return p * x;
}

DEV float normal_from_bits(uint32_t bits) {
  float f = __uint_as_float((bits >> 9) | 0x3F800000u) - 1.0f;
  const float lo = -0.99999994f;            // nextafter(-1, 0) in f32
  float u = fmaf(f, 2.0f, lo);
  u = fmaxf(u, lo);
  return 1.41421356f * erfinv_f32(u);
}

DEV unsigned short f2bf(float f) {   // RTNE f32 -> bf16
  uint32_t u = __float_as_uint(f);
  uint32_t r = u + 0x7FFFu + ((u >> 16) & 1u);
  return (unsigned short)(r >> 16);
}

// ---------------- CSR build ----------------
__global__ void count_kernel(const int* __restrict__ rows, const int* __restrict__ cols,
                             int* __restrict__ counts, int* __restrict__ degs, int E) {
  int e = blockIdx.x * blockDim.x + threadIdx.x;
  if (e < E) {
    int r = rows[e];
    atomicAdd(&counts[r], 1);
    if (r != cols[e]) atomicAdd(&degs[r], 1);
  }
}

__global__ void dinv_kernel(const int* __restrict__ degs, float* __restrict__ dinv, int N) {
  int i = blockIdx.x * blockDim.x + threadIdx.x;
  if (i < N) {
    int d = degs[i];
    dinv[i] = d > 0 ? rsqrtf((float)d) : 0.0f;
  }
}

#define SCAN_T 1024
__global__ __launch_bounds__(SCAN_T) void scan_kernel(const int* __restrict__ counts,
                                                      int* __restrict__ row_ptr,
                                                      int* __restrict__ cursor, int N) {
  __shared__ int sa[SCAN_T], sb[SCAN_T];
  const int t = threadIdx.x;
  const int CH = (N + SCAN_T - 1) / SCAN_T;
  int base = t * CH;
  int psum = 0;
  for (int k = 0; k < CH; ++k) {
    int idx = base + k;
    if (idx < N) psum += counts[idx];
  }
  sa[t] = psum;
  __syncthreads();
  int* src = sa; int* dst = sb;
  for (int off = 1; off < SCAN_T; off <<= 1) {
    int v = src[t];
    if (t >= off) v += src[t - off];
    dst[t] = v;
    __syncthreads();
    int* tmp = src; src = dst; dst = tmp;
  }
  int running = src[t] - psum;
  for (int k = 0; k < CH; ++k) {
    int idx = base + k;
    if (idx < N) {
      row_ptr[idx] = running;
      cursor[idx] = running;
      running += counts[idx];
    }
  }
  if (t == SCAN_T - 1) row_ptr[N] = running;
}

__global__ void fill_kernel(const int* __restrict__ rows, const int* __restrict__ cols,
                            const float* __restrict__ dinv, int* __restrict__ cursor,
                            float2* __restrict__ ecv, int E) {
  int e = blockIdx.x * blockDim.x + threadIdx.x;
  if (e < E) {
    int r = rows[e], c = cols[e];
    float w = (r != c) ? -dinv[r] * dinv[c] : 0.0f;
    int pos = atomicAdd(&cursor[r], 1);
    ecv[pos] = make_float2(__int_as_float(c), w);
  }
}

// ---------------- propagation: one wave per node, full row per edge ----------------
// SUB=0: outf = P x (f32, padded stride), outb = bf16 copy
// SUB=1: outb = bf16(2*P x - xsub)   (no f32 output)
template <int VEC, int SUB>
__global__ __launch_bounds__(256) void gather_prop_kernel(
    const int* __restrict__ row_ptr, const float2* __restrict__ ecv,
    const float* __restrict__ xsrc, int src_stride,
    const float* __restrict__ xsub, int sub_stride,
    float* __restrict__ outf, unsigned short* __restrict__ outb,
    int N, int F, int Fpad) {
  const int wave = threadIdx.x >> 6, lane = threadIdx.x & 63;
  const int node = blockIdx.x * 4 + wave;
  if (node >= N) return;
  const int f0 = lane * VEC;
  if (f0 >= Fpad) return;
  const bool live = (f0 + VEC) <= F;
  float acc[VEC] = {};
  if (live) {
    const int s = row_ptr[node], e = row_ptr[node + 1];
    for (int j = s; j < e; ++j) {
      float2 cw = ecv[j];                              // wave-uniform
      int c = __float_as_int(cw.x);
      const float* src = xsrc + (size_t)c * src_stride + f0;
      if (VEC == 4) {
        float4 v = *(const float4*)src;
        acc[0] = fmaf(cw.y, v.x, acc[0]); acc[1] = fmaf(cw.y, v.y, acc[1]);
        acc[2] = fmaf(cw.y, v.z, acc[2]); acc[3] = fmaf(cw.y, v.w, acc[3]);
      } else {
        float2 v = *(const float2*)src;
        acc[0] = fmaf(cw.y, v.x, acc[0]); acc[1] = fmaf(cw.y, v.y, acc[1]);
      }
    }
    if (SUB) {
      const float* sb = xsub + (size_t)node * sub_stride + f0;
#pragma unroll
      for (int q = 0; q < VEC; ++q) acc[q] = fmaf(2.0f, acc[q], -sb[q]);
    }
  }
  size_t ob = (size_t)node * Fpad + f0;
  if (!SUB) {
#pragma unroll
    for (int q = 0; q < VEC; ++q) outf[ob + q] = acc[q];
  }
  if (VEC == 4) {
    uint2 u;
    u.x = (uint32_t)f2bf(acc[0]) | ((uint32_t)f2bf(acc[1]) << 16);
    u.y = (uint32_t)f2bf(acc[2]) | ((uint32_t)f2bf(acc[3]) << 16);
    *(uint2*)&outb[ob] = u;
  } else {
    uint32_t u = (uint32_t)f2bf(acc[0]) | ((uint32_t)f2bf(acc[1]) << 16);
    *(uint32_t*)&outb[ob] = u;
  }
}

// ---------------- weight transpose+convert: Wt[p][o][k] = bf16(W[p][k][o]) ----------------
__global__ void wtrans_kernel(const float* __restrict__ W, unsigned short* __restrict__ Wt,
                              int F, int Fpad, int O) {
  int idx = blockIdx.x * 256 + threadIdx.x;
  int total = 3 * O * Fpad;
  if (idx >= total) return;
  int k = idx % Fpad;
  int o = (idx / Fpad) % O;
  int p = idx / (Fpad * O);
  Wt[idx] = (k < F) ? f2bf(W[((size_t)p * F + k) * O + o]) : (unsigned short)0;
}

// ---------------- MFMA bf16 GEMM: out = relu(A0@W0+A1@W1+A2@W2+b)*noise ----------------
// 512 threads = 8 waves (2 M x 4 O); block tile 64 x (NO16*64)
#define LDST 40   // LDS row stride (bf16): breaks b128 bank conflicts (2-way max)
template <int NO16>
__global__ __launch_bounds__(512) void gemm3_mfma_kernel(
    const float* __restrict__ A0f, const unsigned short* __restrict__ A1b,
    const unsigned short* __restrict__ A2b,
    const unsigned short* __restrict__ Wt, const float* __restrict__ bias,
    int M, int F, int Fpad, int a0s, int O, float* __restrict__ out, int fold) {
  constexpr int BN = NO16 * 64;
  __shared__ unsigned short sA[64 * LDST];
  __shared__ unsigned short sB[BN * LDST];
  const int tid = threadIdx.x;
  const int lane = tid & 63;
  const int wave = tid >> 6;
  const int wm = wave >> 2;        // 0..1
  const int wo = wave & 3;         // 0..3
  const int bm = blockIdx.x * 64;
  const int bo = blockIdx.y * BN;

  f32x4 acc[2][NO16] = {};

  for (int p = 0; p < 3; ++p) {
    const unsigned short* __restrict__ Wp = Wt + (size_t)p * O * Fpad;
    const unsigned short* __restrict__ Ab = (p == 1) ? A1b : A2b;
    for (int k0 = 0; k0 < Fpad; k0 += 32) {
      __syncthreads();
      if (tid < 256) {   // stage A tile: 64 rows x 32 k
        int row = tid >> 2, ch = (tid & 3) * 8;
        int gm = bm + row;
        u16x8 vv = {};
        if (gm < M) {
          if (p == 0) {
            int kk = k0 + ch;
            unsigned short pk[8];
            if (kk + 8 <= F) {
#pragma unroll
              for (int j = 0; j < 4; ++j) {
                float2 v2 = *(const float2*)(A0f + (size_t)gm * a0s + kk + 2 * j);
                pk[2 * j] = f2bf(v2.x); pk[2 * j + 1] = f2bf(v2.y);
              }
            } else {
#pragma unroll
              for (int j = 0; j < 8; ++j) {
                int gk = kk + j;
                pk[j] = (gk < F) ? f2bf(A0f[(size_t)gm * a0s + gk]) : (unsigned short)0;
              }
            }
            vv = *(u16x8*)pk;
          } else {
            vv = *(const u16x8*)(Ab + (size_t)gm * Fpad + k0 + ch);
          }
        }
        *(u16x8*)&sA[row * LDST + ch] = vv;
      }
      // stage B tile: BN rows x 32 k (bf16, contiguous)
      for (int idx = tid; idx < BN * 4; idx += 512) {
        int row = idx >> 2, ch = (idx & 3) * 8;
        int go = bo + row;
        u16x8 vv = *(const u16x8*)(Wp + (size_t)go * Fpad + k0 + ch);
        *(u16x8*)&sB[row * LDST + ch] = vv;
      }
      __syncthreads();
      const int kg = (lane >> 4) * 8;
      bf16x8 af[2], bfr[NO16];
#pragma unroll
      for (int mi = 0; mi < 2; ++mi)
        af[mi] = *(const bf16x8*)&sA[(wm * 32 + mi * 16 + (lane & 15)) * LDST + kg];
#pragma unroll
      for (int ni = 0; ni < NO16; ++ni)
        bfr[ni] = *(const bf16x8*)&sB[(wo * (NO16 * 16) + ni * 16 + (lane & 15)) * LDST + kg];
#pragma unroll
      for (int mi = 0; mi < 2; ++mi)
#pragma unroll
        for (int ni = 0; ni < NO16; ++ni)
          acc[mi][ni] = __builtin_amdgcn_mfma_f32_16x16x32_bf16(af[mi], bfr[ni], acc[mi][ni], 0, 0, 0);
    }
  }

  // epilogue: bias + relu + threefry noise
  uint32_t f0 = 0u, f1 = (uint32_t)fold;
  threefry2x32(0u, 42u, f0, f1);
  const int col0 = bo + wo * (NO16 * 16) + (lane & 15);
  const int rbase = bm + wm * 32 + (lane >> 4) * 4;
#pragma unroll
  for (int mi = 0; mi < 2; ++mi) {
#pragma unroll
    for (int r = 0; r < 4; ++r) {
      int gm = rbase + mi * 16 + r;
      if (gm >= M) continue;
#pragma unroll
      for (int ni = 0; ni < NO16; ++ni) {
        int go = col0 + ni * 16;
        float vv = acc[mi][ni][r] + bias[go];
        vv = vv > 0.0f ? vv : 0.0f;
        uint32_t a = 0u, b = (uint32_t)(gm * O + go);
        threefry2x32(f0, f1, a, b);
        out[(size_t)gm * O + go] = vv * normal_from_bits(a ^ b);
      }
    }
  }
}

// ---------------- host orchestration ----------------
extern "C" void kernel_launch(void* const* d_in, const int* in_sizes, int n_in,
                              void* d_out, int out_size, void* d_ws, size_t ws_size,
                              hipStream_t stream) {
  const float* v    = (const float*)d_in[0];
  const int*  edges = (const int*)d_in[1];
  const float* W1 = (const float*)d_in[2];
  const float* b1 = (const float*)d_in[3];
  const float* W2 = (const float*)d_in[4];
  const float* b2 = (const float*)d_in[5];
  const float* W3 = (const float*)d_in[6];
  const float* b3 = (const float*)d_in[7];
  float* out = (float*)d_out;

  const int N = in_sizes[0] / 86;
  const int E = in_sizes[1] / 2;
  const int* rows = edges;
  const int* cols = edges + E;

  // ws layout: ecv[2E f32] | tx1[N*256 f32] | tx1b[N*256 u16] | tx2b[N*256 u16]
  //            | Wt[3*512*256 u16] | counts,degs,row_ptr,cursor,dinv
  float* wsf = (float*)d_ws;
  float2* ecv = (float2*)wsf;
  float* tx1 = wsf + (size_t)2 * E;
  unsigned short* tx1b = (unsigned short*)(tx1 + (size_t)N * 256);
  unsigned short* tx2b = tx1b + (size_t)N * 256;
  unsigned short* Wt = tx2b + (size_t)N * 256;
  int* counts = (int*)(Wt + 3 * 512 * 256);
  int* degs = counts + N;
  int* row_ptr = degs + N;
  int* cursor = row_ptr + (N + 1);
  float* dinv = (float*)(cursor + N);

  float* x1 = out;
  float* x2 = x1 + (size_t)N * 128;
  float* x3 = x2 + (size_t)N * 256;

  // CSR build + norm
  hipMemsetAsync(counts, 0, (size_t)2 * N * sizeof(int), stream);
  count_kernel<<<(E + 255) / 256, 256, 0, stream>>>(rows, cols, counts, degs, E);
  dinv_kernel<<<(N + 255) / 256, 256, 0, stream>>>(degs, dinv, N);
  scan_kernel<<<1, SCAN_T, 0, stream>>>(counts, row_ptr, cursor, N);
  fill_kernel<<<(E + 255) / 256, 256, 0, stream>>>(rows, cols, dinv, cursor, ecv, E);

  const int pblocks = (N + 3) / 4;

  // ---- layer 1: F=86 (pad 96), O=128, VEC=2, NO16=2 ----
  {
    int wtot = 3 * 128 * 96;
    wtrans_kernel<<<(wtot + 255) / 256, 256, 0, stream>>>(W1, Wt, 86, 96, 128);
    gather_prop_kernel<2, 0><<<pblocks, 256, 0, stream>>>(row_ptr, ecv, v, 86, nullptr, 0, tx1, tx1b, N, 86, 96);
    gather_prop_kernel<2, 1><<<pblocks, 256, 0, stream>>>(row_ptr, ecv, tx1, 96, v, 86, nullptr, tx2b, N, 86, 96);
    dim3 g((N + 63) / 64, 1);
    gemm3_mfma_kernel<2><<<g, 512, 0, stream>>>(v, tx1b, tx2b, Wt, b1, N, 86, 96, 86, 128, x1, 1);
  }
  // ---- layer 2: F=128, O=256, VEC=2, NO16=4 ----
  {
    int wtot = 3 * 256 * 128;
    wtrans_kernel<<<(wtot + 255) / 256, 256, 0, stream>>>(W2, Wt, 128, 128, 256);
    gather_prop_kernel<2, 0><<<pblocks, 256, 0, stream>>>(row_ptr, ecv, x1, 128, nullptr, 0, tx1, tx1b, N, 128, 128);
    gather_prop_kernel<2, 1><<<pblocks, 256, 0, stream>>>(row_ptr, ecv, tx1, 128, x1, 128, nullptr, tx2b, N, 128, 128);
    dim3 g((N + 63) / 64, 1);
    gemm3_mfma_kernel<4><<<g, 512, 0, stream>>>(x1, tx1b, tx2b, Wt, b2, N, 128, 128, 128, 256, x2, 2);
  }
  // ---- layer 3: F=256, O=512, VEC=4, NO16=4 ----
  {
    int wtot = 3 * 512 * 256;
    wtrans_kernel<<<(wtot + 255) / 256, 256, 0, stream>>>(W3, Wt, 256, 256, 512);
    gather_prop_kernel<4, 0><<<pblocks, 256, 0, stream>>>(row_ptr, ecv, x2, 256, nullptr, 0, tx1, tx1b, N, 256, 256);
    gather_prop_kernel<4, 1><<<pblocks, 256, 0, stream>>>(row_ptr, ecv, tx1, 256, x2, 256, nullptr, tx2b, N, 256, 256);
    dim3 g((N + 63) / 64, 2);
    gemm3_mfma_kernel<4><<<g, 512, 0, stream>>>(x2, tx1b, tx2b, Wt, b3, N, 256, 256, 256, 512, x3, 3);
  }
}